// Round 2
// baseline (275.711 us; speedup 1.0000x reference)
//
#include <hip/hip_runtime.h>
#include <math.h>

// Problem constants
#define S 64
#define F 10
#define K 7
#define D 512
#define HH 196   // H*H = 14*14
#define DT 128
#define NF (S*F)          // 640
#define NROWS_V (S*F*K)   // 4480
#define NROWS_A (S*K)     // 448
#define NOUT (S*K*F)      // 4480

// ---------------------------------------------------------------------------
// Kernel 1: fg[n][k][c] = (sum_hw feat[n][c][hw] * cam[n][k][hw]) / (sum_hw cam[n][k][hw] + 1e-10)
// One block per n. cam (7x196) hoisted into registers per lane (lanes 0..48
// hold float4 chunks), cam_sum inverse folded into the cam registers.
// Per channel: one coalesced float4 load of feat + 28 FMA + shuffle reduce.
// ---------------------------------------------------------------------------
__global__ __launch_bounds__(256) void fg_kernel(
    const float* __restrict__ feat, const float* __restrict__ cam,
    float* __restrict__ fg) {
  const int n = blockIdx.x;
  const int t = threadIdx.x;
  const int lane = t & 63;
  const int wave = t >> 6;
  const bool active = lane < 49;  // 49 * 4 = 196

  const float* camn = cam + (size_t)n * K * HH;
  float4 camv[K];
#pragma unroll
  for (int k = 0; k < K; ++k) {
    if (active)
      camv[k] = *reinterpret_cast<const float4*>(camn + k * HH + 4 * lane);
    else
      camv[k] = make_float4(0.f, 0.f, 0.f, 0.f);
  }
  // cam_sum per k, fold 1/(sum+1e-10) into camv
#pragma unroll
  for (int k = 0; k < K; ++k) {
    float s = camv[k].x + camv[k].y + camv[k].z + camv[k].w;
#pragma unroll
    for (int m = 32; m >= 1; m >>= 1) s += __shfl_xor(s, m, 64);
    float inv = 1.0f / (s + 1e-10f);
    camv[k].x *= inv; camv[k].y *= inv; camv[k].z *= inv; camv[k].w *= inv;
  }

  const float* featn = feat + (size_t)n * D * HH;
  float* outn = fg + (size_t)n * K * D;

  for (int c = wave; c < D; c += 4) {
    float4 v = make_float4(0.f, 0.f, 0.f, 0.f);
    if (active)
      v = *reinterpret_cast<const float4*>(featn + (size_t)c * HH + 4 * lane);
    float acc[K];
#pragma unroll
    for (int k = 0; k < K; ++k)
      acc[k] = v.x * camv[k].x + v.y * camv[k].y + v.z * camv[k].z + v.w * camv[k].w;
#pragma unroll
    for (int m = 32; m >= 1; m >>= 1) {
#pragma unroll
      for (int k = 0; k < K; ++k) acc[k] += __shfl_xor(acc[k], m, 64);
    }
    // lane k stores output k (static-index select to keep acc in registers)
    float r = acc[0];
    r = (lane == 1) ? acc[1] : r;
    r = (lane == 2) ? acc[2] : r;
    r = (lane == 3) ? acc[3] : r;
    r = (lane == 4) ? acc[4] : r;
    r = (lane == 5) ? acc[5] : r;
    r = (lane == 6) ? acc[6] : r;
    if (lane < K) outn[lane * D + c] = r;
  }
}

// ---------------------------------------------------------------------------
// Kernel 2: fused 2-layer MLP + affine.
//   h = relu(x @ W1 + b1); y = h @ W2 + b2; out = y * g + bn
// 16 rows per block staged in LDS; thread tile = 2 rows x 4 outputs.
// W1/W2 streamed from global (L2-resident: 256 KB / 64 KB).
// ---------------------------------------------------------------------------
__device__ __forceinline__ void fma4(float4& acc, float sx, const float4& wv) {
  acc.x += sx * wv.x; acc.y += sx * wv.y; acc.z += sx * wv.z; acc.w += sx * wv.w;
}

__global__ __launch_bounds__(256) void mlp_kernel(
    const float* __restrict__ X,
    const float* __restrict__ W1, const float* __restrict__ b1,
    const float* __restrict__ W2, const float* __restrict__ b2,
    const float* __restrict__ g, const float* __restrict__ bn,
    float* __restrict__ out) {
  __shared__ float xs[16 * D];
  __shared__ float hs[16 * DT];
  const int t = threadIdx.x;
  const int r0 = blockIdx.x * 16;

  // stage 16 rows of X (16*512 floats = 2048 float4)
  {
    const float4* src = reinterpret_cast<const float4*>(X + (size_t)r0 * D);
    float4* dst = reinterpret_cast<float4*>(xs);
#pragma unroll
    for (int i = 0; i < 8; ++i) dst[t + i * 256] = src[t + i * 256];
  }
  __syncthreads();

  const int jt = t & 31;
  const int j0 = jt * 4;
  const int rt = t >> 5;  // 0..7 ; rows rt and rt+8

  // ---- layer 1 ----
  float4 a0 = *reinterpret_cast<const float4*>(b1 + j0);
  float4 a1 = a0;
  for (int d = 0; d < D; d += 4) {
    float4 xa = *reinterpret_cast<const float4*>(xs + rt * D + d);
    float4 xb = *reinterpret_cast<const float4*>(xs + (rt + 8) * D + d);
    float4 w0 = *reinterpret_cast<const float4*>(W1 + (size_t)(d + 0) * DT + j0);
    float4 w1 = *reinterpret_cast<const float4*>(W1 + (size_t)(d + 1) * DT + j0);
    float4 w2 = *reinterpret_cast<const float4*>(W1 + (size_t)(d + 2) * DT + j0);
    float4 w3 = *reinterpret_cast<const float4*>(W1 + (size_t)(d + 3) * DT + j0);
    fma4(a0, xa.x, w0); fma4(a0, xa.y, w1); fma4(a0, xa.z, w2); fma4(a0, xa.w, w3);
    fma4(a1, xb.x, w0); fma4(a1, xb.y, w1); fma4(a1, xb.z, w2); fma4(a1, xb.w, w3);
  }
  // relu + store h
  a0.x = fmaxf(a0.x, 0.f); a0.y = fmaxf(a0.y, 0.f); a0.z = fmaxf(a0.z, 0.f); a0.w = fmaxf(a0.w, 0.f);
  a1.x = fmaxf(a1.x, 0.f); a1.y = fmaxf(a1.y, 0.f); a1.z = fmaxf(a1.z, 0.f); a1.w = fmaxf(a1.w, 0.f);
  *reinterpret_cast<float4*>(hs + rt * DT + j0) = a0;
  *reinterpret_cast<float4*>(hs + (rt + 8) * DT + j0) = a1;
  __syncthreads();

  // ---- layer 2 ----
  float4 c0 = *reinterpret_cast<const float4*>(b2 + j0);
  float4 c1 = c0;
  for (int d = 0; d < DT; d += 4) {
    float4 xa = *reinterpret_cast<const float4*>(hs + rt * DT + d);
    float4 xb = *reinterpret_cast<const float4*>(hs + (rt + 8) * DT + d);
    float4 w0 = *reinterpret_cast<const float4*>(W2 + (size_t)(d + 0) * DT + j0);
    float4 w1 = *reinterpret_cast<const float4*>(W2 + (size_t)(d + 1) * DT + j0);
    float4 w2 = *reinterpret_cast<const float4*>(W2 + (size_t)(d + 2) * DT + j0);
    float4 w3 = *reinterpret_cast<const float4*>(W2 + (size_t)(d + 3) * DT + j0);
    fma4(c0, xa.x, w0); fma4(c0, xa.y, w1); fma4(c0, xa.z, w2); fma4(c0, xa.w, w3);
    fma4(c1, xb.x, w0); fma4(c1, xb.y, w1); fma4(c1, xb.z, w2); fma4(c1, xb.w, w3);
  }
  // affine epilogue
  float4 gv = *reinterpret_cast<const float4*>(g + j0);
  float4 bv = *reinterpret_cast<const float4*>(bn + j0);
  float4 o0, o1;
  o0.x = c0.x * gv.x + bv.x; o0.y = c0.y * gv.y + bv.y;
  o0.z = c0.z * gv.z + bv.z; o0.w = c0.w * gv.w + bv.w;
  o1.x = c1.x * gv.x + bv.x; o1.y = c1.y * gv.y + bv.y;
  o1.z = c1.z * gv.z + bv.z; o1.w = c1.w * gv.w + bv.w;
  *reinterpret_cast<float4*>(out + (size_t)(r0 + rt) * DT + j0) = o0;
  *reinterpret_cast<float4*>(out + (size_t)(r0 + rt + 8) * DT + j0) = o1;
}

// ---------------------------------------------------------------------------
// Kernel 3: losses + masks. One wave (block of 64) per (s,k,f).
// out layout: [0..4479] loss_co*mask_co, [4480..8959] loss_di*mask_di,
//             [8960..13439] mask_co, [13440..17919] mask_di
// ---------------------------------------------------------------------------
__global__ __launch_bounds__(64) void loss_kernel(
    const float* __restrict__ Ta, const float* __restrict__ Tv,
    const float* __restrict__ pred_a, const float* __restrict__ pred_v,
    const int* __restrict__ perm_idx, const int* __restrict__ cls_idx,
    float* __restrict__ out) {
  const int idx = blockIdx.x;  // s*70 + k*10 + f
  const int f = idx % F;
  const int k = (idx / F) % K;
  const int s = idx / (K * F);
  const int lane = threadIdx.x;

  const int p = perm_idx[idx];
  const int c = cls_idx[idx];
  const int rowd = ((s ^ 1) * F + p) * K + c;

  float d1 = 0.f, d2 = 0.f;
  if (lane < 32) {
    float4 ta = reinterpret_cast<const float4*>(Ta)[(s * K + k) * 32 + lane];
    float4 tv = reinterpret_cast<const float4*>(Tv)[((s * F + f) * K + k) * 32 + lane];
    float4 td = reinterpret_cast<const float4*>(Tv)[rowd * 32 + lane];
    float e;
    e = ta.x - tv.x; d1 += e * e;
    e = ta.y - tv.y; d1 += e * e;
    e = ta.z - tv.z; d1 += e * e;
    e = ta.w - tv.w; d1 += e * e;
    e = ta.x - td.x; d2 += e * e;
    e = ta.y - td.y; d2 += e * e;
    e = ta.z - td.z; d2 += e * e;
    e = ta.w - td.w; d2 += e * e;
  }
#pragma unroll
  for (int m = 16; m >= 1; m >>= 1) {
    d1 += __shfl_xor(d1, m, 64);
    d2 += __shfl_xor(d2, m, 64);
  }
  if (lane == 0) {
    float pa = pred_a[s * K + k];
    bool act = pa > 0.3f;
    int num = (int)floorf(pa * (float)F);
    float pvv = pred_v[(s * F + f) * K + k];
    float sg = 1.0f / (1.0f + expf(-pvv));
    bool mco = act && (sg > 0.3f);
    bool mdi = act && (f < num);
    float lco = d1 * (1.0f / 128.0f);
    float ldi = d2 * (1.0f / 128.0f);
    out[idx] = mco ? lco : 0.0f;
    out[NOUT + idx] = mdi ? ldi : 0.0f;
    out[2 * NOUT + idx] = mco ? 1.0f : 0.0f;
    out[3 * NOUT + idx] = mdi ? 1.0f : 0.0f;
  }
}

extern "C" void kernel_launch(void* const* d_in, const int* in_sizes, int n_in,
                              void* d_out, int out_size, void* d_ws, size_t ws_size,
                              hipStream_t stream) {
  const float* feat_a     = (const float*)d_in[0];
  const float* pred_a     = (const float*)d_in[1];
  const float* feat_v_raw = (const float*)d_in[2];
  const float* pred_v     = (const float*)d_in[3];
  const float* cam        = (const float*)d_in[4];
  const float* W1a = (const float*)d_in[5];
  const float* b1a = (const float*)d_in[6];
  const float* W2a = (const float*)d_in[7];
  const float* b2a = (const float*)d_in[8];
  const float* ga  = (const float*)d_in[9];
  const float* bna = (const float*)d_in[10];
  const float* W1v = (const float*)d_in[11];
  const float* b1v = (const float*)d_in[12];
  const float* W2v = (const float*)d_in[13];
  const float* b2v = (const float*)d_in[14];
  const float* gv  = (const float*)d_in[15];
  const float* bnv = (const float*)d_in[16];
  const int* perm_idx = (const int*)d_in[17];
  const int* cls_idx  = (const int*)d_in[18];
  float* out = (float*)d_out;

  // workspace layout (floats): fg[640*7*512] | Ta[448*128] | Tv[4480*128]
  float* ws = (float*)d_ws;
  float* fg = ws;
  float* Ta = fg + (size_t)NF * K * D;        // 2,293,760
  float* Tv = Ta + (size_t)NROWS_A * DT;      // + 57,344

  fg_kernel<<<NF, 256, 0, stream>>>(feat_v_raw, cam, fg);
  mlp_kernel<<<NROWS_A / 16, 256, 0, stream>>>(feat_a, W1a, b1a, W2a, b2a, ga, bna, Ta);
  mlp_kernel<<<NROWS_V / 16, 256, 0, stream>>>(fg, W1v, b1v, W2v, b2v, gv, bnv, Tv);
  loss_kernel<<<NOUT, 64, 0, stream>>>(Ta, Tv, pred_a, pred_v, perm_idx, cls_idx, out);
}

// Round 3
// 175.356 us; speedup vs baseline: 1.5723x; 1.5723x over previous
//
#include <hip/hip_runtime.h>
#include <math.h>

// Problem constants
#define S 64
#define F 10
#define K 7
#define D 512
#define HH 196   // H*H = 14*14
#define DT 128
#define NF (S*F)          // 640
#define NROWS_V (S*F*K)   // 4480
#define NROWS_A (S*K)     // 448
#define NOUT (S*K*F)      // 4480

// ---------------------------------------------------------------------------
// Kernel 1 (v2): fg[n][k][c] = (sum_hw feat[n][c][hw] * cam[n][k][hw]) / (cam_sum[n][k] + 1e-10)
//
// Grid: 1280 blocks = 640 n x 2 channel-halves (exactly 5 blocks/CU).
// Block: 128 threads; thread owns channels c0 = half*256 + t, c1 = c0+128,
// accumulating acc[2][7] in registers over all 196 hw (no shuffles).
// feat is staged per hw-tile (28 floats x 256 ch = 28,672 B) into LDS via
// global_load_lds (async DMA), double-buffered: STAGE(next) -> compute(cur)
// -> __syncthreads() (drains vmcnt).
// LDS layout is piece-linear = [c_local][7 float4] (28-dword rows: bank step
// 4 -> b128-baseline, no extra conflicts).
// cam is read with block-uniform addresses -> scalar loads; normalization
// applied once at the end (matches reference op order: einsum then divide).
// ---------------------------------------------------------------------------
__device__ __forceinline__ void stage_tile(const float* featn, float* dst,
                                           int tile, int wave, int lane) {
  // 1792 float4 pieces per tile; 28 wave-issues of 64 x 16 B; wave w takes
  // issues i = w, w+2, ...  Piece p = i*64+lane -> (c = p/7, j = p%7);
  // LDS slot p == c*7+j, i.e. rows of 7 float4 per channel.
#pragma unroll
  for (int ii = 0; ii < 14; ++ii) {
    const int i = 2 * ii + wave;
    const int p = i * 64 + lane;
    const int c = p / 7;
    const int j = p - c * 7;
    const float* src = featn + (size_t)c * HH + tile * 28 + j * 4;
    __builtin_amdgcn_global_load_lds(
        (const __attribute__((address_space(1))) void*)src,
        (__attribute__((address_space(3))) void*)(dst + i * 256), 16, 0, 0);
  }
}

__global__ __launch_bounds__(128) void fg_kernel(
    const float* __restrict__ feat, const float* __restrict__ cam,
    float* __restrict__ fg) {
  __shared__ float buf[2][7168];   // 2 x 28,672 B double buffer
  __shared__ float inv_lds[K];

  const int t = threadIdx.x;
  const int lane = t & 63;
  const int wave = t >> 6;
  const int n = blockIdx.x >> 1;
  const int half = blockIdx.x & 1;
  const int c0blk = half * 256;

  const float* featn = feat + ((size_t)n * D + c0blk) * HH;
  const float* camn = cam + (size_t)n * K * HH;

  // cam sums -> inv_lds[k] (wave 0 only; butterfly over 64 lanes)
  if (t < 64) {
    const bool act = lane < 49;  // 49*4 = 196
#pragma unroll
    for (int k = 0; k < K; ++k) {
      float4 cv = act ? *reinterpret_cast<const float4*>(camn + k * HH + 4 * lane)
                      : make_float4(0.f, 0.f, 0.f, 0.f);
      float s = cv.x + cv.y + cv.z + cv.w;
#pragma unroll
      for (int m = 32; m >= 1; m >>= 1) s += __shfl_xor(s, m, 64);
      if (lane == 0) inv_lds[k] = 1.0f / (s + 1e-10f);
    }
  }

  // prologue: stage tile 0
  stage_tile(featn, &buf[0][0], 0, wave, lane);
  __syncthreads();

  float a0[K], a1[K];
#pragma unroll
  for (int k = 0; k < K; ++k) { a0[k] = 0.f; a1[k] = 0.f; }

  for (int tile = 0; tile < 7; ++tile) {
    const int cur = tile & 1;
    if (tile < 6) stage_tile(featn, &buf[cur ^ 1][0], tile + 1, wave, lane);

    const float4* bp = reinterpret_cast<const float4*>(&buf[cur][0]);
    const float* camt = camn + tile * 28;
#pragma unroll
    for (int j = 0; j < 7; ++j) {
      float4 f0 = bp[t * 7 + j];
      float4 f1 = bp[(t + 128) * 7 + j];
#pragma unroll
      for (int k = 0; k < K; ++k) {
        const float4 cv = *reinterpret_cast<const float4*>(camt + k * HH + j * 4);
        a0[k] = fmaf(f0.x, cv.x, a0[k]);
        a0[k] = fmaf(f0.y, cv.y, a0[k]);
        a0[k] = fmaf(f0.z, cv.z, a0[k]);
        a0[k] = fmaf(f0.w, cv.w, a0[k]);
        a1[k] = fmaf(f1.x, cv.x, a1[k]);
        a1[k] = fmaf(f1.y, cv.y, a1[k]);
        a1[k] = fmaf(f1.z, cv.z, a1[k]);
        a1[k] = fmaf(f1.w, cv.w, a1[k]);
      }
    }
    __syncthreads();  // drains vmcnt (staged tile ready) + guards buffer reuse
  }

  float* fgn = fg + (size_t)n * K * D + c0blk;
#pragma unroll
  for (int k = 0; k < K; ++k) {
    const float iv = inv_lds[k];
    fgn[k * D + t] = a0[k] * iv;
    fgn[k * D + t + 128] = a1[k] * iv;
  }
}

// ---------------------------------------------------------------------------
// Kernel 2: fused 2-layer MLP + affine (unchanged, verified-correct).
// ---------------------------------------------------------------------------
__device__ __forceinline__ void fma4(float4& acc, float sx, const float4& wv) {
  acc.x += sx * wv.x; acc.y += sx * wv.y; acc.z += sx * wv.z; acc.w += sx * wv.w;
}

__global__ __launch_bounds__(256) void mlp_kernel(
    const float* __restrict__ X,
    const float* __restrict__ W1, const float* __restrict__ b1,
    const float* __restrict__ W2, const float* __restrict__ b2,
    const float* __restrict__ g, const float* __restrict__ bn,
    float* __restrict__ out) {
  __shared__ float xs[16 * D];
  __shared__ float hs[16 * DT];
  const int t = threadIdx.x;
  const int r0 = blockIdx.x * 16;

  {
    const float4* src = reinterpret_cast<const float4*>(X + (size_t)r0 * D);
    float4* dst = reinterpret_cast<float4*>(xs);
#pragma unroll
    for (int i = 0; i < 8; ++i) dst[t + i * 256] = src[t + i * 256];
  }
  __syncthreads();

  const int jt = t & 31;
  const int j0 = jt * 4;
  const int rt = t >> 5;

  float4 a0 = *reinterpret_cast<const float4*>(b1 + j0);
  float4 a1 = a0;
  for (int d = 0; d < D; d += 4) {
    float4 xa = *reinterpret_cast<const float4*>(xs + rt * D + d);
    float4 xb = *reinterpret_cast<const float4*>(xs + (rt + 8) * D + d);
    float4 w0 = *reinterpret_cast<const float4*>(W1 + (size_t)(d + 0) * DT + j0);
    float4 w1 = *reinterpret_cast<const float4*>(W1 + (size_t)(d + 1) * DT + j0);
    float4 w2 = *reinterpret_cast<const float4*>(W1 + (size_t)(d + 2) * DT + j0);
    float4 w3 = *reinterpret_cast<const float4*>(W1 + (size_t)(d + 3) * DT + j0);
    fma4(a0, xa.x, w0); fma4(a0, xa.y, w1); fma4(a0, xa.z, w2); fma4(a0, xa.w, w3);
    fma4(a1, xb.x, w0); fma4(a1, xb.y, w1); fma4(a1, xb.z, w2); fma4(a1, xb.w, w3);
  }
  a0.x = fmaxf(a0.x, 0.f); a0.y = fmaxf(a0.y, 0.f); a0.z = fmaxf(a0.z, 0.f); a0.w = fmaxf(a0.w, 0.f);
  a1.x = fmaxf(a1.x, 0.f); a1.y = fmaxf(a1.y, 0.f); a1.z = fmaxf(a1.z, 0.f); a1.w = fmaxf(a1.w, 0.f);
  *reinterpret_cast<float4*>(hs + rt * DT + j0) = a0;
  *reinterpret_cast<float4*>(hs + (rt + 8) * DT + j0) = a1;
  __syncthreads();

  float4 c0 = *reinterpret_cast<const float4*>(b2 + j0);
  float4 c1 = c0;
  for (int d = 0; d < DT; d += 4) {
    float4 xa = *reinterpret_cast<const float4*>(hs + rt * DT + d);
    float4 xb = *reinterpret_cast<const float4*>(hs + (rt + 8) * DT + d);
    float4 w0 = *reinterpret_cast<const float4*>(W2 + (size_t)(d + 0) * DT + j0);
    float4 w1 = *reinterpret_cast<const float4*>(W2 + (size_t)(d + 1) * DT + j0);
    float4 w2 = *reinterpret_cast<const float4*>(W2 + (size_t)(d + 2) * DT + j0);
    float4 w3 = *reinterpret_cast<const float4*>(W2 + (size_t)(d + 3) * DT + j0);
    fma4(c0, xa.x, w0); fma4(c0, xa.y, w1); fma4(c0, xa.z, w2); fma4(c0, xa.w, w3);
    fma4(c1, xb.x, w0); fma4(c1, xb.y, w1); fma4(c1, xb.z, w2); fma4(c1, xb.w, w3);
  }
  float4 gv = *reinterpret_cast<const float4*>(g + j0);
  float4 bv = *reinterpret_cast<const float4*>(bn + j0);
  float4 o0, o1;
  o0.x = c0.x * gv.x + bv.x; o0.y = c0.y * gv.y + bv.y;
  o0.z = c0.z * gv.z + bv.z; o0.w = c0.w * gv.w + bv.w;
  o1.x = c1.x * gv.x + bv.x; o1.y = c1.y * gv.y + bv.y;
  o1.z = c1.z * gv.z + bv.z; o1.w = c1.w * gv.w + bv.w;
  *reinterpret_cast<float4*>(out + (size_t)(r0 + rt) * DT + j0) = o0;
  *reinterpret_cast<float4*>(out + (size_t)(r0 + rt + 8) * DT + j0) = o1;
}

// ---------------------------------------------------------------------------
// Kernel 3: losses + masks (unchanged, verified-correct).
// ---------------------------------------------------------------------------
__global__ __launch_bounds__(64) void loss_kernel(
    const float* __restrict__ Ta, const float* __restrict__ Tv,
    const float* __restrict__ pred_a, const float* __restrict__ pred_v,
    const int* __restrict__ perm_idx, const int* __restrict__ cls_idx,
    float* __restrict__ out) {
  const int idx = blockIdx.x;
  const int f = idx % F;
  const int k = (idx / F) % K;
  const int s = idx / (K * F);
  const int lane = threadIdx.x;

  const int p = perm_idx[idx];
  const int c = cls_idx[idx];
  const int rowd = ((s ^ 1) * F + p) * K + c;

  float d1 = 0.f, d2 = 0.f;
  if (lane < 32) {
    float4 ta = reinterpret_cast<const float4*>(Ta)[(s * K + k) * 32 + lane];
    float4 tv = reinterpret_cast<const float4*>(Tv)[((s * F + f) * K + k) * 32 + lane];
    float4 td = reinterpret_cast<const float4*>(Tv)[rowd * 32 + lane];
    float e;
    e = ta.x - tv.x; d1 += e * e;
    e = ta.y - tv.y; d1 += e * e;
    e = ta.z - tv.z; d1 += e * e;
    e = ta.w - tv.w; d1 += e * e;
    e = ta.x - td.x; d2 += e * e;
    e = ta.y - td.y; d2 += e * e;
    e = ta.z - td.z; d2 += e * e;
    e = ta.w - td.w; d2 += e * e;
  }
#pragma unroll
  for (int m = 16; m >= 1; m >>= 1) {
    d1 += __shfl_xor(d1, m, 64);
    d2 += __shfl_xor(d2, m, 64);
  }
  if (lane == 0) {
    float pa = pred_a[s * K + k];
    bool act = pa > 0.3f;
    int num = (int)floorf(pa * (float)F);
    float pvv = pred_v[(s * F + f) * K + k];
    float sg = 1.0f / (1.0f + expf(-pvv));
    bool mco = act && (sg > 0.3f);
    bool mdi = act && (f < num);
    float lco = d1 * (1.0f / 128.0f);
    float ldi = d2 * (1.0f / 128.0f);
    out[idx] = mco ? lco : 0.0f;
    out[NOUT + idx] = mdi ? ldi : 0.0f;
    out[2 * NOUT + idx] = mco ? 1.0f : 0.0f;
    out[3 * NOUT + idx] = mdi ? 1.0f : 0.0f;
  }
}

extern "C" void kernel_launch(void* const* d_in, const int* in_sizes, int n_in,
                              void* d_out, int out_size, void* d_ws, size_t ws_size,
                              hipStream_t stream) {
  const float* feat_a     = (const float*)d_in[0];
  const float* pred_a     = (const float*)d_in[1];
  const float* feat_v_raw = (const float*)d_in[2];
  const float* pred_v     = (const float*)d_in[3];
  const float* cam        = (const float*)d_in[4];
  const float* W1a = (const float*)d_in[5];
  const float* b1a = (const float*)d_in[6];
  const float* W2a = (const float*)d_in[7];
  const float* b2a = (const float*)d_in[8];
  const float* ga  = (const float*)d_in[9];
  const float* bna = (const float*)d_in[10];
  const float* W1v = (const float*)d_in[11];
  const float* b1v = (const float*)d_in[12];
  const float* W2v = (const float*)d_in[13];
  const float* b2v = (const float*)d_in[14];
  const float* gv  = (const float*)d_in[15];
  const float* bnv = (const float*)d_in[16];
  const int* perm_idx = (const int*)d_in[17];
  const int* cls_idx  = (const int*)d_in[18];
  float* out = (float*)d_out;

  // workspace layout (floats): fg[640*7*512] | Ta[448*128] | Tv[4480*128]
  float* ws = (float*)d_ws;
  float* fg = ws;
  float* Ta = fg + (size_t)NF * K * D;
  float* Tv = Ta + (size_t)NROWS_A * DT;

  fg_kernel<<<NF * 2, 128, 0, stream>>>(feat_v_raw, cam, fg);
  mlp_kernel<<<NROWS_A / 16, 256, 0, stream>>>(feat_a, W1a, b1a, W2a, b2a, ga, bna, Ta);
  mlp_kernel<<<NROWS_V / 16, 256, 0, stream>>>(fg, W1v, b1v, W2v, b2v, gv, bnv, Tv);
  loss_kernel<<<NOUT, 64, 0, stream>>>(Ta, Tv, pred_a, pred_v, perm_idx, cls_idx, out);
}

// Round 4
// 163.240 us; speedup vs baseline: 1.6890x; 1.0742x over previous
//
#include <hip/hip_runtime.h>
#include <math.h>

// Problem constants
#define S 64
#define F 10
#define K 7
#define D 512
#define HH 196   // H*H = 14*14
#define DT 128
#define NF (S*F)          // 640
#define NROWS_V (S*F*K)   // 4480
#define NROWS_A (S*K)     // 448
#define NOUT (S*K*F)      // 4480
#define MLP_R 8
#define NA_BLK (NROWS_A / MLP_R)   // 56
#define NV_BLK (NROWS_V / MLP_R)   // 560

// ---------------------------------------------------------------------------
// Kernel 1: fg[n][k][c] = (sum_hw feat[n][c][hw] * cam[n][k][hw]) / (cam_sum + 1e-10)
// (unchanged from R3 — theory: HBM-bound ~41-46 us)
// ---------------------------------------------------------------------------
__device__ __forceinline__ void stage_tile(const float* featn, float* dst,
                                           int tile, int wave, int lane) {
#pragma unroll
  for (int ii = 0; ii < 14; ++ii) {
    const int i = 2 * ii + wave;
    const int p = i * 64 + lane;
    const int c = p / 7;
    const int j = p - c * 7;
    const float* src = featn + (size_t)c * HH + tile * 28 + j * 4;
    __builtin_amdgcn_global_load_lds(
        (const __attribute__((address_space(1))) void*)src,
        (__attribute__((address_space(3))) void*)(dst + i * 256), 16, 0, 0);
  }
}

__global__ __launch_bounds__(128) void fg_kernel(
    const float* __restrict__ feat, const float* __restrict__ cam,
    float* __restrict__ fg) {
  __shared__ float buf[2][7168];
  __shared__ float inv_lds[K];

  const int t = threadIdx.x;
  const int lane = t & 63;
  const int wave = t >> 6;
  const int n = blockIdx.x >> 1;
  const int half = blockIdx.x & 1;
  const int c0blk = half * 256;

  const float* featn = feat + ((size_t)n * D + c0blk) * HH;
  const float* camn = cam + (size_t)n * K * HH;

  if (t < 64) {
    const bool act = lane < 49;
#pragma unroll
    for (int k = 0; k < K; ++k) {
      float4 cv = act ? *reinterpret_cast<const float4*>(camn + k * HH + 4 * lane)
                      : make_float4(0.f, 0.f, 0.f, 0.f);
      float s = cv.x + cv.y + cv.z + cv.w;
#pragma unroll
      for (int m = 32; m >= 1; m >>= 1) s += __shfl_xor(s, m, 64);
      if (lane == 0) inv_lds[k] = 1.0f / (s + 1e-10f);
    }
  }

  stage_tile(featn, &buf[0][0], 0, wave, lane);
  __syncthreads();

  float a0[K], a1[K];
#pragma unroll
  for (int k = 0; k < K; ++k) { a0[k] = 0.f; a1[k] = 0.f; }

  for (int tile = 0; tile < 7; ++tile) {
    const int cur = tile & 1;
    if (tile < 6) stage_tile(featn, &buf[cur ^ 1][0], tile + 1, wave, lane);

    const float4* bp = reinterpret_cast<const float4*>(&buf[cur][0]);
    const float* camt = camn + tile * 28;
#pragma unroll
    for (int j = 0; j < 7; ++j) {
      float4 f0 = bp[t * 7 + j];
      float4 f1 = bp[(t + 128) * 7 + j];
#pragma unroll
      for (int k = 0; k < K; ++k) {
        const float4 cv = *reinterpret_cast<const float4*>(camt + k * HH + j * 4);
        a0[k] = fmaf(f0.x, cv.x, a0[k]);
        a0[k] = fmaf(f0.y, cv.y, a0[k]);
        a0[k] = fmaf(f0.z, cv.z, a0[k]);
        a0[k] = fmaf(f0.w, cv.w, a0[k]);
        a1[k] = fmaf(f1.x, cv.x, a1[k]);
        a1[k] = fmaf(f1.y, cv.y, a1[k]);
        a1[k] = fmaf(f1.z, cv.z, a1[k]);
        a1[k] = fmaf(f1.w, cv.w, a1[k]);
      }
    }
    __syncthreads();
  }

  float* fgn = fg + (size_t)n * K * D + c0blk;
#pragma unroll
  for (int k = 0; k < K; ++k) {
    const float iv = inv_lds[k];
    fgn[k * D + t] = a0[k] * iv;
    fgn[k * D + t + 128] = a1[k] * iv;
  }
}

// ---------------------------------------------------------------------------
// Kernel 2 (v2): BOTH MLPs in one dispatch. 8 rows/block, 256 threads,
// thread = 1 row x 4 cols (2.6K-inst serial chain, ~8 blocks/CU possible).
// Blocks [0,56): A-problem; [56,616): V-problem.
// ---------------------------------------------------------------------------
__device__ __forceinline__ void fma4(float4& acc, float sx, const float4& wv) {
  acc.x += sx * wv.x; acc.y += sx * wv.y; acc.z += sx * wv.z; acc.w += sx * wv.w;
}

__global__ __launch_bounds__(256) void mlp2_kernel(
    const float* __restrict__ Xa, const float* __restrict__ Xv,
    const float* __restrict__ W1a, const float* __restrict__ b1a,
    const float* __restrict__ W2a, const float* __restrict__ b2a,
    const float* __restrict__ ga, const float* __restrict__ bna,
    const float* __restrict__ W1v, const float* __restrict__ b1v,
    const float* __restrict__ W2v, const float* __restrict__ b2v,
    const float* __restrict__ gv, const float* __restrict__ bnv,
    float* __restrict__ Ta, float* __restrict__ Tv) {
  __shared__ float xs[MLP_R * D];
  __shared__ float hs[MLP_R * DT];
  const int t = threadIdx.x;
  const int b = blockIdx.x;

  const float *X, *W1, *b1, *W2, *b2, *g, *bn;
  float* out;
  int r0;
  if (b < NA_BLK) {
    X = Xa; W1 = W1a; b1 = b1a; W2 = W2a; b2 = b2a; g = ga; bn = bna;
    out = Ta; r0 = b * MLP_R;
  } else {
    X = Xv; W1 = W1v; b1 = b1v; W2 = W2v; b2 = b2v; g = gv; bn = bnv;
    out = Tv; r0 = (b - NA_BLK) * MLP_R;
  }

  // stage 8 rows of X (1024 float4)
  {
    const float4* src = reinterpret_cast<const float4*>(X + (size_t)r0 * D);
    float4* dst = reinterpret_cast<float4*>(xs);
#pragma unroll
    for (int i = 0; i < 4; ++i) dst[t + i * 256] = src[t + i * 256];
  }
  __syncthreads();

  const int j0 = (t & 31) * 4;
  const int rt = t >> 5;  // 0..7, one row per thread

  // ---- layer 1 ----
  float4 a0 = *reinterpret_cast<const float4*>(b1 + j0);
  for (int d = 0; d < D; d += 4) {
    float4 xa = *reinterpret_cast<const float4*>(xs + rt * D + d);
    float4 w0 = *reinterpret_cast<const float4*>(W1 + (size_t)(d + 0) * DT + j0);
    float4 w1 = *reinterpret_cast<const float4*>(W1 + (size_t)(d + 1) * DT + j0);
    float4 w2 = *reinterpret_cast<const float4*>(W1 + (size_t)(d + 2) * DT + j0);
    float4 w3 = *reinterpret_cast<const float4*>(W1 + (size_t)(d + 3) * DT + j0);
    fma4(a0, xa.x, w0); fma4(a0, xa.y, w1); fma4(a0, xa.z, w2); fma4(a0, xa.w, w3);
  }
  a0.x = fmaxf(a0.x, 0.f); a0.y = fmaxf(a0.y, 0.f);
  a0.z = fmaxf(a0.z, 0.f); a0.w = fmaxf(a0.w, 0.f);
  *reinterpret_cast<float4*>(hs + rt * DT + j0) = a0;
  __syncthreads();

  // ---- layer 2 ----
  float4 c0 = *reinterpret_cast<const float4*>(b2 + j0);
  for (int d = 0; d < DT; d += 4) {
    float4 xa = *reinterpret_cast<const float4*>(hs + rt * DT + d);
    float4 w0 = *reinterpret_cast<const float4*>(W2 + (size_t)(d + 0) * DT + j0);
    float4 w1 = *reinterpret_cast<const float4*>(W2 + (size_t)(d + 1) * DT + j0);
    float4 w2 = *reinterpret_cast<const float4*>(W2 + (size_t)(d + 2) * DT + j0);
    float4 w3 = *reinterpret_cast<const float4*>(W2 + (size_t)(d + 3) * DT + j0);
    fma4(c0, xa.x, w0); fma4(c0, xa.y, w1); fma4(c0, xa.z, w2); fma4(c0, xa.w, w3);
  }
  float4 gvv = *reinterpret_cast<const float4*>(g + j0);
  float4 bv = *reinterpret_cast<const float4*>(bn + j0);
  float4 o0;
  o0.x = c0.x * gvv.x + bv.x; o0.y = c0.y * gvv.y + bv.y;
  o0.z = c0.z * gvv.z + bv.z; o0.w = c0.w * gvv.w + bv.w;
  *reinterpret_cast<float4*>(out + (size_t)(r0 + rt) * DT + j0) = o0;
}

// ---------------------------------------------------------------------------
// Kernel 3 (v2): losses + masks. 256 threads/block, 8 units/block
// (32-lane group per unit), 560 blocks.
// ---------------------------------------------------------------------------
__global__ __launch_bounds__(256) void loss_kernel(
    const float* __restrict__ Ta, const float* __restrict__ Tv,
    const float* __restrict__ pred_a, const float* __restrict__ pred_v,
    const int* __restrict__ perm_idx, const int* __restrict__ cls_idx,
    float* __restrict__ out) {
  const int t = threadIdx.x;
  const int sub = t & 31;
  const int idx = blockIdx.x * 8 + (t >> 5);  // unit = s*70 + k*10 + f
  const int f = idx % F;
  const int k = (idx / F) % K;
  const int s = idx / (K * F);

  const int p = perm_idx[idx];
  const int c = cls_idx[idx];
  const int rowd = ((s ^ 1) * F + p) * K + c;

  float4 ta = reinterpret_cast<const float4*>(Ta)[(s * K + k) * 32 + sub];
  float4 tv = reinterpret_cast<const float4*>(Tv)[((s * F + f) * K + k) * 32 + sub];
  float4 td = reinterpret_cast<const float4*>(Tv)[rowd * 32 + sub];
  float d1 = 0.f, d2 = 0.f, e;
  e = ta.x - tv.x; d1 += e * e;
  e = ta.y - tv.y; d1 += e * e;
  e = ta.z - tv.z; d1 += e * e;
  e = ta.w - tv.w; d1 += e * e;
  e = ta.x - td.x; d2 += e * e;
  e = ta.y - td.y; d2 += e * e;
  e = ta.z - td.z; d2 += e * e;
  e = ta.w - td.w; d2 += e * e;
#pragma unroll
  for (int m = 16; m >= 1; m >>= 1) {  // stays within each 32-lane group
    d1 += __shfl_xor(d1, m, 64);
    d2 += __shfl_xor(d2, m, 64);
  }
  if (sub == 0) {
    float pa = pred_a[s * K + k];
    bool act = pa > 0.3f;
    int num = (int)floorf(pa * (float)F);
    float pvv = pred_v[(s * F + f) * K + k];
    float sg = 1.0f / (1.0f + expf(-pvv));
    bool mco = act && (sg > 0.3f);
    bool mdi = act && (f < num);
    float lco = d1 * (1.0f / 128.0f);
    float ldi = d2 * (1.0f / 128.0f);
    out[idx] = mco ? lco : 0.0f;
    out[NOUT + idx] = mdi ? ldi : 0.0f;
    out[2 * NOUT + idx] = mco ? 1.0f : 0.0f;
    out[3 * NOUT + idx] = mdi ? 1.0f : 0.0f;
  }
}

extern "C" void kernel_launch(void* const* d_in, const int* in_sizes, int n_in,
                              void* d_out, int out_size, void* d_ws, size_t ws_size,
                              hipStream_t stream) {
  const float* feat_a     = (const float*)d_in[0];
  const float* pred_a     = (const float*)d_in[1];
  const float* feat_v_raw = (const float*)d_in[2];
  const float* pred_v     = (const float*)d_in[3];
  const float* cam        = (const float*)d_in[4];
  const float* W1a = (const float*)d_in[5];
  const float* b1a = (const float*)d_in[6];
  const float* W2a = (const float*)d_in[7];
  const float* b2a = (const float*)d_in[8];
  const float* ga  = (const float*)d_in[9];
  const float* bna = (const float*)d_in[10];
  const float* W1v = (const float*)d_in[11];
  const float* b1v = (const float*)d_in[12];
  const float* W2v = (const float*)d_in[13];
  const float* b2v = (const float*)d_in[14];
  const float* gv  = (const float*)d_in[15];
  const float* bnv = (const float*)d_in[16];
  const int* perm_idx = (const int*)d_in[17];
  const int* cls_idx  = (const int*)d_in[18];
  float* out = (float*)d_out;

  // workspace layout (floats): fg[640*7*512] | Ta[448*128] | Tv[4480*128]
  float* ws = (float*)d_ws;
  float* fg = ws;
  float* Ta = fg + (size_t)NF * K * D;
  float* Tv = Ta + (size_t)NROWS_A * DT;

  fg_kernel<<<NF * 2, 128, 0, stream>>>(feat_v_raw, cam, fg);
  mlp2_kernel<<<NA_BLK + NV_BLK, 256, 0, stream>>>(
      feat_a, fg, W1a, b1a, W2a, b2a, ga, bna,
      W1v, b1v, W2v, b2v, gv, bnv, Ta, Tv);
  loss_kernel<<<NOUT / 8, 256, 0, stream>>>(Ta, Tv, pred_a, pred_v, perm_idx, cls_idx, out);
}

// Round 5
// 149.417 us; speedup vs baseline: 1.8452x; 1.0925x over previous
//
#include <hip/hip_runtime.h>
#include <math.h>

// Problem constants
#define S 64
#define F 10
#define K 7
#define D 512
#define HH 196   // H*H = 14*14
#define DT 128
#define NF (S*F)          // 640
#define NROWS_V (S*F*K)   // 4480
#define NROWS_A (S*K)     // 448
#define NOUT (S*K*F)      // 4480
#define MLP_R 8
#define NA_BLK (NROWS_A / MLP_R)   // 56
#define NV_BLK (NROWS_V / MLP_R)   // 560

// fg kernel geometry
#define FG_TPB 128
#define CH_TILE 16
#define TILE_F4 784     // 16 ch * 196 hw / 4 = float4 count per tile (12,544 B contiguous)
#define TILE_SLOTS 832  // 13 issues * 64 lanes (slots >=784 are clamp-garbage, never read)
#define N_ISSUE 13

// ---------------------------------------------------------------------------
// Kernel 1 (v3): fg[n][k][c] = (sum_hw feat[n][c][hw]*cam[n][k][hw]) / (cam_sum+1e-10)
// Channel-tiled: each staged tile = 16 channels x full 196 hw = ONE contiguous
// 12.5 KB region of feat -> perfectly streaming global_load_lds, no over-fetch.
// 8 threads per channel split the 49-float4 dot; 3-level shuffle reduce.
// cam (7x196) staged to LDS once (8-lane broadcast reads). Double-buffered,
// one barrier per tile. LDS 32.1 KB -> 5 blocks/CU.
// ---------------------------------------------------------------------------
__device__ __forceinline__ void fg_stage(const float* region, float4* dst,
                                         int wave, int lane) {
#pragma unroll
  for (int i = wave; i < N_ISSUE; i += 2) {
    const int p = i * 64 + lane;
    const int ps = (p < TILE_F4) ? p : 0;  // clamp: avoid OOB on last tile
    __builtin_amdgcn_global_load_lds(
        (const __attribute__((address_space(1))) void*)(region + (size_t)ps * 4),
        (__attribute__((address_space(3))) void*)(dst + i * 64), 16, 0, 0);
  }
}

__global__ __launch_bounds__(FG_TPB) void fg_kernel(
    const float* __restrict__ feat, const float* __restrict__ cam,
    float* __restrict__ fg) {
  __shared__ float4 buf[2][TILE_SLOTS];   // 26,624 B
  __shared__ float4 cam_lds[K * 49];      // 5,488 B
  __shared__ float inv_lds[K];

  const int t = threadIdx.x;
  const int lane = t & 63;
  const int wave = t >> 6;
  const int n = blockIdx.x >> 1;
  const int half = blockIdx.x & 1;
  const int c0blk = half * 256;

  const float* featn = feat + ((size_t)n * D + c0blk) * HH;
  const float* camn = cam + (size_t)n * K * HH;

  // stage cam into LDS (343 float4, contiguous)
  for (int p = t; p < K * 49; p += FG_TPB)
    cam_lds[p] = reinterpret_cast<const float4*>(camn)[p];

  // cam sums -> inv_lds[k] (wave 0)
  if (t < 64) {
    const bool act = lane < 49;
#pragma unroll
    for (int k = 0; k < K; ++k) {
      float4 cv = act ? *reinterpret_cast<const float4*>(camn + k * HH + 4 * lane)
                      : make_float4(0.f, 0.f, 0.f, 0.f);
      float s = cv.x + cv.y + cv.z + cv.w;
#pragma unroll
      for (int m = 32; m >= 1; m >>= 1) s += __shfl_xor(s, m, 64);
      if (lane == 0) inv_lds[k] = 1.0f / (s + 1e-10f);
    }
  }

  // prologue: stage tile 0
  fg_stage(featn, &buf[0][0], wave, lane);
  __syncthreads();

  const int cl = t >> 3;  // channel-in-tile 0..15
  const int s8 = t & 7;   // 8-way hw split

  for (int tt = 0; tt < D / CH_TILE / 2; ++tt) {  // 16 tiles
    const int cur = tt & 1;
    if (tt < 15)
      fg_stage(featn + (size_t)(tt + 1) * TILE_F4 * 4, &buf[cur ^ 1][0], wave, lane);

    const float4* frow = &buf[cur][cl * 49];
    float acc[K];
#pragma unroll
    for (int k = 0; k < K; ++k) acc[k] = 0.f;

#pragma unroll
    for (int jj = 0; jj < 6; ++jj) {
      const int j = 6 * s8 + jj;
      const float4 fv = frow[j];
#pragma unroll
      for (int k = 0; k < K; ++k) {
        const float4 cv = cam_lds[k * 49 + j];
        acc[k] = fmaf(fv.x, cv.x, acc[k]);
        acc[k] = fmaf(fv.y, cv.y, acc[k]);
        acc[k] = fmaf(fv.z, cv.z, acc[k]);
        acc[k] = fmaf(fv.w, cv.w, acc[k]);
      }
    }
    if (s8 == 7) {  // j = 48 leftover
      const float4 fv = frow[48];
#pragma unroll
      for (int k = 0; k < K; ++k) {
        const float4 cv = cam_lds[k * 49 + 48];
        acc[k] = fmaf(fv.x, cv.x, acc[k]);
        acc[k] = fmaf(fv.y, cv.y, acc[k]);
        acc[k] = fmaf(fv.z, cv.z, acc[k]);
        acc[k] = fmaf(fv.w, cv.w, acc[k]);
      }
    }

    // reduce across the 8-lane group (xor 1,2,4)
#pragma unroll
    for (int m = 1; m <= 4; m <<= 1) {
#pragma unroll
      for (int k = 0; k < K; ++k) acc[k] += __shfl_xor(acc[k], m, 64);
    }

    if (s8 == 0) {
      const int c = c0blk + tt * CH_TILE + cl;
      float* fgn = fg + (size_t)n * K * D + c;
#pragma unroll
      for (int k = 0; k < K; ++k) fgn[k * D] = acc[k] * inv_lds[k];
    }
    __syncthreads();  // drains staged tile (vmcnt) + guards buffer reuse
  }
}

// ---------------------------------------------------------------------------
// Kernel 2: BOTH MLPs in one dispatch (unchanged from R4).
// ---------------------------------------------------------------------------
__device__ __forceinline__ void fma4(float4& acc, float sx, const float4& wv) {
  acc.x += sx * wv.x; acc.y += sx * wv.y; acc.z += sx * wv.z; acc.w += sx * wv.w;
}

__global__ __launch_bounds__(256) void mlp2_kernel(
    const float* __restrict__ Xa, const float* __restrict__ Xv,
    const float* __restrict__ W1a, const float* __restrict__ b1a,
    const float* __restrict__ W2a, const float* __restrict__ b2a,
    const float* __restrict__ ga, const float* __restrict__ bna,
    const float* __restrict__ W1v, const float* __restrict__ b1v,
    const float* __restrict__ W2v, const float* __restrict__ b2v,
    const float* __restrict__ gv, const float* __restrict__ bnv,
    float* __restrict__ Ta, float* __restrict__ Tv) {
  __shared__ float xs[MLP_R * D];
  __shared__ float hs[MLP_R * DT];
  const int t = threadIdx.x;
  const int b = blockIdx.x;

  const float *X, *W1, *b1, *W2, *b2, *g, *bn;
  float* out;
  int r0;
  if (b < NA_BLK) {
    X = Xa; W1 = W1a; b1 = b1a; W2 = W2a; b2 = b2a; g = ga; bn = bna;
    out = Ta; r0 = b * MLP_R;
  } else {
    X = Xv; W1 = W1v; b1 = b1v; W2 = W2v; b2 = b2v; g = gv; bn = bnv;
    out = Tv; r0 = (b - NA_BLK) * MLP_R;
  }

  {
    const float4* src = reinterpret_cast<const float4*>(X + (size_t)r0 * D);
    float4* dst = reinterpret_cast<float4*>(xs);
#pragma unroll
    for (int i = 0; i < 4; ++i) dst[t + i * 256] = src[t + i * 256];
  }
  __syncthreads();

  const int j0 = (t & 31) * 4;
  const int rt = t >> 5;

  float4 a0 = *reinterpret_cast<const float4*>(b1 + j0);
  for (int d = 0; d < D; d += 4) {
    float4 xa = *reinterpret_cast<const float4*>(xs + rt * D + d);
    float4 w0 = *reinterpret_cast<const float4*>(W1 + (size_t)(d + 0) * DT + j0);
    float4 w1 = *reinterpret_cast<const float4*>(W1 + (size_t)(d + 1) * DT + j0);
    float4 w2 = *reinterpret_cast<const float4*>(W1 + (size_t)(d + 2) * DT + j0);
    float4 w3 = *reinterpret_cast<const float4*>(W1 + (size_t)(d + 3) * DT + j0);
    fma4(a0, xa.x, w0); fma4(a0, xa.y, w1); fma4(a0, xa.z, w2); fma4(a0, xa.w, w3);
  }
  a0.x = fmaxf(a0.x, 0.f); a0.y = fmaxf(a0.y, 0.f);
  a0.z = fmaxf(a0.z, 0.f); a0.w = fmaxf(a0.w, 0.f);
  *reinterpret_cast<float4*>(hs + rt * DT + j0) = a0;
  __syncthreads();

  float4 c0 = *reinterpret_cast<const float4*>(b2 + j0);
  for (int d = 0; d < DT; d += 4) {
    float4 xa = *reinterpret_cast<const float4*>(hs + rt * DT + d);
    float4 w0 = *reinterpret_cast<const float4*>(W2 + (size_t)(d + 0) * DT + j0);
    float4 w1 = *reinterpret_cast<const float4*>(W2 + (size_t)(d + 1) * DT + j0);
    float4 w2 = *reinterpret_cast<const float4*>(W2 + (size_t)(d + 2) * DT + j0);
    float4 w3 = *reinterpret_cast<const float4*>(W2 + (size_t)(d + 3) * DT + j0);
    fma4(c0, xa.x, w0); fma4(c0, xa.y, w1); fma4(c0, xa.z, w2); fma4(c0, xa.w, w3);
  }
  float4 gvv = *reinterpret_cast<const float4*>(g + j0);
  float4 bv = *reinterpret_cast<const float4*>(bn + j0);
  float4 o0;
  o0.x = c0.x * gvv.x + bv.x; o0.y = c0.y * gvv.y + bv.y;
  o0.z = c0.z * gvv.z + bv.z; o0.w = c0.w * gvv.w + bv.w;
  *reinterpret_cast<float4*>(out + (size_t)(r0 + rt) * DT + j0) = o0;
}

// ---------------------------------------------------------------------------
// Kernel 3: losses + masks (unchanged from R4).
// ---------------------------------------------------------------------------
__global__ __launch_bounds__(256) void loss_kernel(
    const float* __restrict__ Ta, const float* __restrict__ Tv,
    const float* __restrict__ pred_a, const float* __restrict__ pred_v,
    const int* __restrict__ perm_idx, const int* __restrict__ cls_idx,
    float* __restrict__ out) {
  const int t = threadIdx.x;
  const int sub = t & 31;
  const int idx = blockIdx.x * 8 + (t >> 5);
  const int f = idx % F;
  const int k = (idx / F) % K;
  const int s = idx / (K * F);

  const int p = perm_idx[idx];
  const int c = cls_idx[idx];
  const int rowd = ((s ^ 1) * F + p) * K + c;

  float4 ta = reinterpret_cast<const float4*>(Ta)[(s * K + k) * 32 + sub];
  float4 tv = reinterpret_cast<const float4*>(Tv)[((s * F + f) * K + k) * 32 + sub];
  float4 td = reinterpret_cast<const float4*>(Tv)[rowd * 32 + sub];
  float d1 = 0.f, d2 = 0.f, e;
  e = ta.x - tv.x; d1 += e * e;
  e = ta.y - tv.y; d1 += e * e;
  e = ta.z - tv.z; d1 += e * e;
  e = ta.w - tv.w; d1 += e * e;
  e = ta.x - td.x; d2 += e * e;
  e = ta.y - td.y; d2 += e * e;
  e = ta.z - td.z; d2 += e * e;
  e = ta.w - td.w; d2 += e * e;
#pragma unroll
  for (int m = 16; m >= 1; m >>= 1) {
    d1 += __shfl_xor(d1, m, 64);
    d2 += __shfl_xor(d2, m, 64);
  }
  if (sub == 0) {
    float pa = pred_a[s * K + k];
    bool act = pa > 0.3f;
    int num = (int)floorf(pa * (float)F);
    float pvv = pred_v[(s * F + f) * K + k];
    float sg = 1.0f / (1.0f + expf(-pvv));
    bool mco = act && (sg > 0.3f);
    bool mdi = act && (f < num);
    float lco = d1 * (1.0f / 128.0f);
    float ldi = d2 * (1.0f / 128.0f);
    out[idx] = mco ? lco : 0.0f;
    out[NOUT + idx] = mdi ? ldi : 0.0f;
    out[2 * NOUT + idx] = mco ? 1.0f : 0.0f;
    out[3 * NOUT + idx] = mdi ? 1.0f : 0.0f;
  }
}

extern "C" void kernel_launch(void* const* d_in, const int* in_sizes, int n_in,
                              void* d_out, int out_size, void* d_ws, size_t ws_size,
                              hipStream_t stream) {
  const float* feat_a     = (const float*)d_in[0];
  const float* pred_a     = (const float*)d_in[1];
  const float* feat_v_raw = (const float*)d_in[2];
  const float* pred_v     = (const float*)d_in[3];
  const float* cam        = (const float*)d_in[4];
  const float* W1a = (const float*)d_in[5];
  const float* b1a = (const float*)d_in[6];
  const float* W2a = (const float*)d_in[7];
  const float* b2a = (const float*)d_in[8];
  const float* ga  = (const float*)d_in[9];
  const float* bna = (const float*)d_in[10];
  const float* W1v = (const float*)d_in[11];
  const float* b1v = (const float*)d_in[12];
  const float* W2v = (const float*)d_in[13];
  const float* b2v = (const float*)d_in[14];
  const float* gv  = (const float*)d_in[15];
  const float* bnv = (const float*)d_in[16];
  const int* perm_idx = (const int*)d_in[17];
  const int* cls_idx  = (const int*)d_in[18];
  float* out = (float*)d_out;

  // workspace layout (floats): fg[640*7*512] | Ta[448*128] | Tv[4480*128]
  float* ws = (float*)d_ws;
  float* fg = ws;
  float* Ta = fg + (size_t)NF * K * D;
  float* Tv = Ta + (size_t)NROWS_A * DT;

  fg_kernel<<<NF * 2, FG_TPB, 0, stream>>>(feat_v_raw, cam, fg);
  mlp2_kernel<<<NA_BLK + NV_BLK, 256, 0, stream>>>(
      feat_a, fg, W1a, b1a, W2a, b2a, ga, bna,
      W1v, b1v, W2v, b2v, gv, bnv, Ta, Tv);
  loss_kernel<<<NOUT / 8, 256, 0, stream>>>(Ta, Tv, pred_a, pred_v, perm_idx, cls_idx, out);
}